// Round 4
// baseline (726.976 us; speedup 1.0000x reference)
//
#include <hip/hip_runtime.h>
#include <stdint.h>

#define N_NODES 8192
#define IN_F    512
#define OUT_F   256
#define ALPHA   0.2f

typedef __attribute__((ext_vector_type(8))) short bf16x8;
typedef __attribute__((ext_vector_type(4))) float f32x4;

__device__ __forceinline__ uint32_t f32_to_bf16(float f) {
    union { float f; uint32_t u; } v; v.f = f;
    uint32_t u = v.u;
    return (u + 0x7fffu + ((u >> 16) & 1u)) >> 16;   // RNE
}

// async global->LDS, 16B per lane; LDS dest = uniform base + lane*16
__device__ __forceinline__ void async_copy16(const void* g, void* l) {
    __builtin_amdgcn_global_load_lds(
        (const __attribute__((address_space(1))) uint32_t*)g,
        (__attribute__((address_space(3))) uint32_t*)l, 16, 0, 0);
}

// ---------------------------------------------------------------------------
// K0: w1 = W^T a1, w2 = W^T a2  (w12[0:512]=w1, w12[512:1024]=w2)
// ---------------------------------------------------------------------------
__global__ __launch_bounds__(256) void k0_wvec(
    const float* __restrict__ W, const float* __restrict__ a_vec,
    float* __restrict__ w12)
{
    const int t  = threadIdx.x;
    const int nb = blockIdx.x * 8;
    float a1lo = 0.f, a1hi = 0.f, a2lo = 0.f, a2hi = 0.f;
    #pragma unroll
    for (int q = 0; q < 8; q++) {
        int n = nb + q;
        float lo = W[(size_t)n * IN_F + t];
        float hi = W[(size_t)n * IN_F + t + 256];
        float a1 = a_vec[n], a2 = a_vec[OUT_F + n];
        a1lo = fmaf(lo, a1, a1lo); a1hi = fmaf(hi, a1, a1hi);
        a2lo = fmaf(lo, a2, a2lo); a2hi = fmaf(hi, a2, a2hi);
    }
    atomicAdd(&w12[t], a1lo);       atomicAdd(&w12[t + 256], a1hi);
    atomicAdd(&w12[512 + t], a2lo); atomicAdd(&w12[512 + t + 256], a2hi);
}

// ---------------------------------------------------------------------------
// Ks: s_src[i] = h[i] . w1 ; s_dst[i] = h[i] . w2   (1 wave per row)
// ---------------------------------------------------------------------------
__global__ __launch_bounds__(256) void ks_svec(
    const float* __restrict__ h, const float* __restrict__ w12,
    float* __restrict__ s_src, float* __restrict__ s_dst)
{
    __shared__ float sw[1024];
    const int t = threadIdx.x;
    #pragma unroll
    for (int q = 0; q < 4; q++) sw[q * 256 + t] = w12[q * 256 + t];
    __syncthreads();
    const int w = t >> 6, ln = t & 63;
    const int i = blockIdx.x * 4 + w;
    const float* hr = h + (size_t)i * IN_F + ln * 8;
    float4 h0 = *(const float4*)hr;
    float4 h1 = *(const float4*)(hr + 4);
    const float* w1 = sw + ln * 8;
    const float* w2 = sw + 512 + ln * 8;
    float v1 = h0.x*w1[0] + h0.y*w1[1] + h0.z*w1[2] + h0.w*w1[3]
             + h1.x*w1[4] + h1.y*w1[5] + h1.z*w1[6] + h1.w*w1[7];
    float v2 = h0.x*w2[0] + h0.y*w2[1] + h0.z*w2[2] + h0.w*w2[3]
             + h1.x*w2[4] + h1.y*w2[5] + h1.z*w2[6] + h1.w*w2[7];
    #pragma unroll
    for (int off = 32; off >= 1; off >>= 1) {
        v1 += __shfl_xor(v1, off, 64);
        v2 += __shfl_xor(v2, off, 64);
    }
    if (ln == 0) { s_src[i] = v1; s_dst[i] = v2; }
}

// ---------------------------------------------------------------------------
// K1: Wh = h @ W^T (fp32) -> whf bf16 in MFMA-B-fragment-major layout.
// chunk c = (j>>5)*16 + (n>>4); within: lane = (n&15) + ((j>>3)&3)*16,
// element = lane*8 + (j&7).   grid (4 colblk, 128 rowblk), 256 thr, 4x4/thr.
// ---------------------------------------------------------------------------
__global__ __launch_bounds__(256) void k1_wh_pack(
    const float* __restrict__ h, const float* __restrict__ W,
    uint16_t* __restrict__ whf)
{
    const int n0 = blockIdx.x * 64, i0 = blockIdx.y * 64;
    const int t  = threadIdx.x;
    const int tn = t & 15, tm = t >> 4;

    __shared__ float As[32][68];
    __shared__ float Bs[32][68];

    float acc[4][4];
    #pragma unroll
    for (int i = 0; i < 4; i++)
        #pragma unroll
        for (int j = 0; j < 4; j++) acc[i][j] = 0.f;

    for (int k0 = 0; k0 < IN_F; k0 += 32) {
        __syncthreads();
        #pragma unroll
        for (int q = 0; q < 2; q++) {
            int u   = q * 256 + t;
            int row = u >> 3;
            int kf  = (u & 7) * 4;
            float4 va = *(const float4*)&h[(size_t)(i0 + row) * IN_F + k0 + kf];
            As[kf + 0][row] = va.x; As[kf + 1][row] = va.y;
            As[kf + 2][row] = va.z; As[kf + 3][row] = va.w;
            float4 vb = *(const float4*)&W[(size_t)(n0 + row) * IN_F + k0 + kf];
            Bs[kf + 0][row] = vb.x; Bs[kf + 1][row] = vb.y;
            Bs[kf + 2][row] = vb.z; Bs[kf + 3][row] = vb.w;
        }
        __syncthreads();
        #pragma unroll
        for (int kk = 0; kk < 32; kk++) {
            float a[4], b[4];
            *(float4*)a = *(const float4*)&As[kk][tm * 4];
            *(float4*)b = *(const float4*)&Bs[kk][tn * 4];
            #pragma unroll
            for (int i = 0; i < 4; i++)
                #pragma unroll
                for (int j = 0; j < 4; j++) acc[i][j] = fmaf(a[i], b[j], acc[i][j]);
        }
    }

    #pragma unroll
    for (int ii = 0; ii < 4; ii++) {
        int gr = i0 + tm * 4 + ii;
        int ck = gr >> 5;
        int lr = (gr >> 3) & 3;
        int jj = gr & 7;
        #pragma unroll
        for (int jn = 0; jn < 4; jn++) {
            int gc   = n0 + tn * 4 + jn;
            int c    = ck * 16 + (gc >> 4);
            int lane = (gc & 15) + lr * 16;
            whf[(size_t)c * 512 + lane * 8 + jj] = (uint16_t)f32_to_bf16(acc[ii][jn]);
        }
    }
}

// ---------------------------------------------------------------------------
// K2: adjacency -> phase-interleaved bitmask + softmax denominators l[i].
// mask layout: word (i, jb, ph) bit b  <->  adj[i][jb*256 + b*4 + ph] > 0.
// ---------------------------------------------------------------------------
__global__ __launch_bounds__(256) void k2_mask_l(
    const float* __restrict__ adj, const float* __restrict__ s_src,
    const float* __restrict__ s_dst, uint64_t* __restrict__ mask,
    float* __restrict__ l_out)
{
    const int i = blockIdx.x;
    const int t = threadIdx.x, w = t >> 6, ln = t & 63;
    const float si = s_src[i];
    const float4* rowv = (const float4*)(adj + (size_t)i * N_NODES);
    const float4* sdv  = (const float4*)s_dst;
    float acc = 0.f;
    #pragma unroll
    for (int it = 0; it < 8; it++) {
        int jb = it * 4 + w;          // 256-j block, 0..31
        int v4 = jb * 64 + ln;
        float4 a  = rowv[v4];
        float4 sd = sdv[v4];
        uint64_t b0 = __ballot(a.x > 0.f);
        uint64_t b1 = __ballot(a.y > 0.f);
        uint64_t b2 = __ballot(a.z > 0.f);
        uint64_t b3 = __ballot(a.w > 0.f);
        if (ln == 0) {
            uint64_t* mw = mask + (size_t)i * 128 + jb * 4;
            mw[0] = b0; mw[1] = b1; mw[2] = b2; mw[3] = b3;
        }
        float x, e;
        x = si + sd.x; e = fmaxf(x, ALPHA * x); if (a.x > 0.f) acc += __expf(e);
        x = si + sd.y; e = fmaxf(x, ALPHA * x); if (a.y > 0.f) acc += __expf(e);
        x = si + sd.z; e = fmaxf(x, ALPHA * x); if (a.z > 0.f) acc += __expf(e);
        x = si + sd.w; e = fmaxf(x, ALPHA * x); if (a.w > 0.f) acc += __expf(e);
    }
    #pragma unroll
    for (int off = 32; off >= 1; off >>= 1) acc += __shfl_xor(acc, off, 64);
    __shared__ float red[4];
    if (ln == 0) red[w] = acc;
    __syncthreads();
    if (t == 0) l_out[i] = (red[0] + red[1]) + (red[2] + red[3]);
}

// ---------------------------------------------------------------------------
// K3: fused attention-write + (attention @ Wh) bf16 MFMA GEMM.
// grid (256 rb, 4 jc), 256 thr. Block: 32 rows x 2048 j, 64 iters of BK=32.
// Per-iteration VMEM queue is EXACTLY [DMA x4, store x2] (order pinned by a
// sched_barrier after the DMA issue; store issued last, after MFMA):
//  - s_dst and mask words for the whole 2048-j range staged into LDS tables
//    in the prologue (zero loop loads);
//  - whf tile (16 KB) double-buffered via global_load_lds; stage t+1 at top;
//  - bottom wait is COUNTED: vmcnt(2) for storing waves / vmcnt(0) for
//    others -> att stores are NEVER waited on, only the DMA is.
// Waves (mh, nh): mh = row half, nh = n half. No split-K -> acc[8], direct
// epilogue store. LDS = 32K whf + 8K sdt + 8.25K mtab -> 3 blocks/CU.
// ---------------------------------------------------------------------------
__global__ __launch_bounds__(256, 3) void k3_att_gemm(
    const uint64_t* __restrict__ mask, const float* __restrict__ s_src,
    const float* __restrict__ s_dst, const float* __restrict__ l_in,
    const uint16_t* __restrict__ whf, float* __restrict__ att_out,
    float* __restrict__ partial)
{
    const int rb = blockIdx.x, jc = blockIdx.y;
    const int i0 = rb * 32, jbase = jc * 2048;
    const int t = threadIdx.x, w = t >> 6, ln = t & 63;
    const int mh = w & 1, nh = w >> 1;

    __shared__ uint16_t whf_lds[2][8192];   // 2 x 16 KB
    __shared__ float    sdt[2048];          // 8 KB: s_dst[jbase .. +2048)
    __shared__ uint64_t mtab[32 * 33];      // 8.25 KB: 32 rows x 32 words, pad 33

    // ---- prologue: stage tables + tile 0 ----
    {
        // s_dst table: 2048 floats, 8 floats/thread
        const float4* s4 = (const float4*)(s_dst + jbase);
        ((float4*)sdt)[t * 2]     = s4[t * 2];
        ((float4*)sdt)[t * 2 + 1] = s4[t * 2 + 1];
        // mask table: row r = t>>3 gets words [(t&7)*4 .. +4)
        int r = t >> 3, c = (t & 7) * 4;
        const uint64_t* mr = mask + (size_t)(i0 + r) * 128 + (jbase >> 8) * 4 + c;
        uint64_t m0 = mr[0], m1 = mr[1], m2 = mr[2], m3 = mr[3];
        uint64_t* md = &mtab[r * 33 + c];
        md[0] = m0; md[1] = m1; md[2] = m2; md[3] = m3;
        // whf tile 0 (16 KB, 4 KB per wave)
        const uint16_t* src = whf + ((size_t)(jbase >> 5)) * 8192;
        #pragma unroll
        for (int q = 0; q < 4; q++) {
            int cchunk = w * 4 + q;
            async_copy16(src + (size_t)cchunk * 512 + ln * 8,
                         &whf_lds[0][cchunk * 512]);
        }
        __builtin_amdgcn_sched_barrier(0);
    }

    const int m   = mh * 16 + (ln & 15);    // row within block, 0..31
    const int kof = (ln >> 4) * 8;          // 0,8,16,24
    const int gi  = i0 + m;

    const float sim = s_src[gi];
    const float il  = 1.0f / l_in[gi];

    f32x4 acc[8];
    #pragma unroll
    for (int b = 0; b < 8; b++) acc[b] = (f32x4){0.f, 0.f, 0.f, 0.f};

    __syncthreads();   // tables + tile 0 ready (full drain, once)

    uint64_t mwv[4];

    for (int it = 0; it < 64; it++) {
        const int cur = it & 1;

        // stage NEXT tile (oldest VMEM ops in this iter's queue)
        if (it < 63) {
            const uint16_t* src =
                whf + ((size_t)(jbase >> 5) + it + 1) * 8192;
            #pragma unroll
            for (int q = 0; q < 4; q++) {
                int cchunk = w * 4 + q;
                async_copy16(src + (size_t)cchunk * 512 + ln * 8,
                             &whf_lds[cur ^ 1][cchunk * 512]);
            }
        }
        // pin queue order: nothing (esp. the att store) moves above the DMAs
        __builtin_amdgcn_sched_barrier(0);

        // mask words for this 256-j group (LDS, bank-spread by pad 33)
        if ((it & 7) == 0) {
            const uint64_t* mp = &mtab[m * 33 + (it >> 3) * 4];
            mwv[0] = mp[0]; mwv[1] = mp[1]; mwv[2] = mp[2]; mwv[3] = mp[3];
        }

        // s_dst from LDS table
        const float* sp = sdt + it * 32 + kof;
        float4 sd0 = *(const float4*)sp;
        float4 sd1 = *(const float4*)(sp + 4);
        float sdv[8] = {sd0.x, sd0.y, sd0.z, sd0.w, sd1.x, sd1.y, sd1.z, sd1.w};

        const int bbase = ((it & 7) << 3) + (kof >> 2);
        float p[8];
        #pragma unroll
        for (int jj = 0; jj < 8; jj++) {
            float x  = sim + sdv[jj];
            float e  = fmaxf(x, ALPHA * x);
            float pe = __expf(e) * il;
            int bidx = bbase + (jj >> 2);
            p[jj] = ((mwv[jj & 3] >> bidx) & 1ull) ? pe : 0.f;
        }

        // pack A-fragment to bf16
        union { bf16x8 v; uint32_t u[4]; } pk;
        #pragma unroll
        for (int q = 0; q < 4; q++)
            pk.u[q] = f32_to_bf16(p[2 * q]) | (f32_to_bf16(p[2 * q + 1]) << 16);
        bf16x8 af = pk.v;

        // B-fragments from LDS (this wave's nh half: 8 x 1 KB)
        const uint16_t* bl = &whf_lds[cur][nh * 8 * 512 + ln * 8];
        #pragma unroll
        for (int nl = 0; nl < 8; nl++) {
            bf16x8 bfr = *(const bf16x8*)(bl + nl * 512);
            acc[nl] = __builtin_amdgcn_mfma_f32_16x16x32_bf16(af, bfr, acc[nl], 0, 0, 0);
        }

        // att store LAST in the VMEM queue (only nh==0; nh duplicates P)
        if (nh == 0) {
            float* go = att_out + (size_t)gi * N_NODES + jbase + it * 32 + kof;
            __builtin_nontemporal_store(*(f32x4*)&p[0], (f32x4*)go);
            __builtin_nontemporal_store(*(f32x4*)&p[4], (f32x4*)(go + 4));
        }

        // counted wait: DMAs (older) retired; this iter's 2 stores may remain
        if (nh == 0) asm volatile("s_waitcnt vmcnt(2)" ::: "memory");
        else         asm volatile("s_waitcnt vmcnt(0)" ::: "memory");
        __builtin_amdgcn_s_barrier();
    }

    // epilogue: each wave owns rows [i0+mh*16,+16) x cols [nh*128,+128).
    // C/D frag: col = lane&15, row = (lane>>4)*4 + reg.
    float* pbase = partial + (size_t)jc * ((size_t)N_NODES * OUT_F);
    const int gr0 = i0 + mh * 16 + (ln >> 4) * 4;
    #pragma unroll
    for (int nl = 0; nl < 8; nl++) {
        int gc = nh * 128 + nl * 16 + (ln & 15);
        #pragma unroll
        for (int r = 0; r < 4; r++)
            pbase[(size_t)(gr0 + r) * OUT_F + gc] = acc[nl][r];
    }
}

// ---------------------------------------------------------------------------
// K4: h_prime = sum of 4 split-K partials
// ---------------------------------------------------------------------------
__global__ __launch_bounds__(256) void k4_reduce(
    const float* __restrict__ partial, float* __restrict__ hp)
{
    const size_t S = (size_t)N_NODES * OUT_F;
    int idx = (blockIdx.x * 256 + threadIdx.x) * 4;
    float4 a = *(const float4*)(partial + idx);
    float4 b = *(const float4*)(partial + S + idx);
    float4 c = *(const float4*)(partial + 2 * S + idx);
    float4 d = *(const float4*)(partial + 3 * S + idx);
    float4 o;
    o.x = (a.x + b.x) + (c.x + d.x);
    o.y = (a.y + b.y) + (c.y + d.y);
    o.z = (a.z + b.z) + (c.z + d.z);
    o.w = (a.w + b.w) + (c.w + d.w);
    *(float4*)(hp + idx) = o;
}

extern "C" void kernel_launch(void* const* d_in, const int* in_sizes, int n_in,
                              void* d_out, int out_size, void* d_ws, size_t ws_size,
                              hipStream_t stream) {
    (void)in_sizes; (void)n_in; (void)out_size; (void)ws_size;
    const float* h     = (const float*)d_in[0];
    const float* adj   = (const float*)d_in[1];
    const float* W     = (const float*)d_in[2];
    const float* a_vec = (const float*)d_in[3];

    char* ws = (char*)d_ws;
    uint16_t* whf  = (uint16_t*)(ws);                          // 4 MB
    uint64_t* mask = (uint64_t*)(ws + ((size_t)4 << 20));      // 8 MB
    float* partial = (float*)(ws + ((size_t)12 << 20));        // 32 MB
    float* w12     = (float*)(ws + ((size_t)44 << 20));        // 4 KB
    float* s_src   = (float*)(ws + ((size_t)44 << 20) + 16384);
    float* s_dst   = (float*)(ws + ((size_t)44 << 20) + 16384 + 32768);
    float* l_buf   = (float*)(ws + ((size_t)44 << 20) + 16384 + 65536);

    float* hp  = (float*)d_out;
    float* att = hp + (size_t)N_NODES * OUT_F;

    hipMemsetAsync(w12, 0, 4096, stream);
    k0_wvec<<<32, 256, 0, stream>>>(W, a_vec, w12);
    ks_svec<<<2048, 256, 0, stream>>>(h, w12, s_src, s_dst);
    k1_wh_pack<<<dim3(4, 128), 256, 0, stream>>>(h, W, whf);
    k2_mask_l<<<8192, 256, 0, stream>>>(adj, s_src, s_dst, mask, l_buf);
    k3_att_gemm<<<dim3(256, 4), 256, 0, stream>>>(mask, s_src, s_dst, l_buf, whf, att, partial);
    k4_reduce<<<2048, 256, 0, stream>>>(partial, hp);
}

// Round 5
// 626.869 us; speedup vs baseline: 1.1597x; 1.1597x over previous
//
#include <hip/hip_runtime.h>
#include <stdint.h>

#define N_NODES 8192
#define IN_F    512
#define OUT_F   256
#define ALPHA   0.2f

typedef __attribute__((ext_vector_type(8))) short bf16x8;
typedef __attribute__((ext_vector_type(4))) float f32x4;

__device__ __forceinline__ uint32_t f32_to_bf16(float f) {
    union { float f; uint32_t u; } v; v.f = f;
    uint32_t u = v.u;
    return (u + 0x7fffu + ((u >> 16) & 1u)) >> 16;   // RNE
}

// async global->LDS, 16B per lane; LDS dest = uniform base + lane*16
__device__ __forceinline__ void async_copy16(const void* g, void* l) {
    __builtin_amdgcn_global_load_lds(
        (const __attribute__((address_space(1))) uint32_t*)g,
        (__attribute__((address_space(3))) uint32_t*)l, 16, 0, 0);
}

// ---------------------------------------------------------------------------
// K0: w1 = W^T a1, w2 = W^T a2  (w12[0:512]=w1, w12[512:1024]=w2)
// ---------------------------------------------------------------------------
__global__ __launch_bounds__(256) void k0_wvec(
    const float* __restrict__ W, const float* __restrict__ a_vec,
    float* __restrict__ w12)
{
    const int t  = threadIdx.x;
    const int nb = blockIdx.x * 8;
    float a1lo = 0.f, a1hi = 0.f, a2lo = 0.f, a2hi = 0.f;
    #pragma unroll
    for (int q = 0; q < 8; q++) {
        int n = nb + q;
        float lo = W[(size_t)n * IN_F + t];
        float hi = W[(size_t)n * IN_F + t + 256];
        float a1 = a_vec[n], a2 = a_vec[OUT_F + n];
        a1lo = fmaf(lo, a1, a1lo); a1hi = fmaf(hi, a1, a1hi);
        a2lo = fmaf(lo, a2, a2lo); a2hi = fmaf(hi, a2, a2hi);
    }
    atomicAdd(&w12[t], a1lo);       atomicAdd(&w12[t + 256], a1hi);
    atomicAdd(&w12[512 + t], a2lo); atomicAdd(&w12[512 + t + 256], a2hi);
}

// ---------------------------------------------------------------------------
// Ks: s_src[i] = h[i] . w1 ; s_dst[i] = h[i] . w2   (1 wave per row)
// ---------------------------------------------------------------------------
__global__ __launch_bounds__(256) void ks_svec(
    const float* __restrict__ h, const float* __restrict__ w12,
    float* __restrict__ s_src, float* __restrict__ s_dst)
{
    __shared__ float sw[1024];
    const int t = threadIdx.x;
    #pragma unroll
    for (int q = 0; q < 4; q++) sw[q * 256 + t] = w12[q * 256 + t];
    __syncthreads();
    const int w = t >> 6, ln = t & 63;
    const int i = blockIdx.x * 4 + w;
    const float* hr = h + (size_t)i * IN_F + ln * 8;
    float4 h0 = *(const float4*)hr;
    float4 h1 = *(const float4*)(hr + 4);
    const float* w1 = sw + ln * 8;
    const float* w2 = sw + 512 + ln * 8;
    float v1 = h0.x*w1[0] + h0.y*w1[1] + h0.z*w1[2] + h0.w*w1[3]
             + h1.x*w1[4] + h1.y*w1[5] + h1.z*w1[6] + h1.w*w1[7];
    float v2 = h0.x*w2[0] + h0.y*w2[1] + h0.z*w2[2] + h0.w*w2[3]
             + h1.x*w2[4] + h1.y*w2[5] + h1.z*w2[6] + h1.w*w2[7];
    #pragma unroll
    for (int off = 32; off >= 1; off >>= 1) {
        v1 += __shfl_xor(v1, off, 64);
        v2 += __shfl_xor(v2, off, 64);
    }
    if (ln == 0) { s_src[i] = v1; s_dst[i] = v2; }
}

// ---------------------------------------------------------------------------
// K1: Wh = h @ W^T (fp32) -> whf bf16 in MFMA-B-fragment-major layout.
// chunk c = (j>>5)*16 + (n>>4); within: lane = (n&15) + ((j>>3)&3)*16,
// element = lane*8 + (j&7).   grid (4 colblk, 128 rowblk), 256 thr, 4x4/thr.
// ---------------------------------------------------------------------------
__global__ __launch_bounds__(256) void k1_wh_pack(
    const float* __restrict__ h, const float* __restrict__ W,
    uint16_t* __restrict__ whf)
{
    const int n0 = blockIdx.x * 64, i0 = blockIdx.y * 64;
    const int t  = threadIdx.x;
    const int tn = t & 15, tm = t >> 4;

    __shared__ float As[32][68];
    __shared__ float Bs[32][68];

    float acc[4][4];
    #pragma unroll
    for (int i = 0; i < 4; i++)
        #pragma unroll
        for (int j = 0; j < 4; j++) acc[i][j] = 0.f;

    for (int k0 = 0; k0 < IN_F; k0 += 32) {
        __syncthreads();
        #pragma unroll
        for (int q = 0; q < 2; q++) {
            int u   = q * 256 + t;
            int row = u >> 3;
            int kf  = (u & 7) * 4;
            float4 va = *(const float4*)&h[(size_t)(i0 + row) * IN_F + k0 + kf];
            As[kf + 0][row] = va.x; As[kf + 1][row] = va.y;
            As[kf + 2][row] = va.z; As[kf + 3][row] = va.w;
            float4 vb = *(const float4*)&W[(size_t)(n0 + row) * IN_F + k0 + kf];
            Bs[kf + 0][row] = vb.x; Bs[kf + 1][row] = vb.y;
            Bs[kf + 2][row] = vb.z; Bs[kf + 3][row] = vb.w;
        }
        __syncthreads();
        #pragma unroll
        for (int kk = 0; kk < 32; kk++) {
            float a[4], b[4];
            *(float4*)a = *(const float4*)&As[kk][tm * 4];
            *(float4*)b = *(const float4*)&Bs[kk][tn * 4];
            #pragma unroll
            for (int i = 0; i < 4; i++)
                #pragma unroll
                for (int j = 0; j < 4; j++) acc[i][j] = fmaf(a[i], b[j], acc[i][j]);
        }
    }

    #pragma unroll
    for (int ii = 0; ii < 4; ii++) {
        int gr = i0 + tm * 4 + ii;
        int ck = gr >> 5;
        int lr = (gr >> 3) & 3;
        int jj = gr & 7;
        #pragma unroll
        for (int jn = 0; jn < 4; jn++) {
            int gc   = n0 + tn * 4 + jn;
            int c    = ck * 16 + (gc >> 4);
            int lane = (gc & 15) + lr * 16;
            whf[(size_t)c * 512 + lane * 8 + jj] = (uint16_t)f32_to_bf16(acc[ii][jn]);
        }
    }
}

// ---------------------------------------------------------------------------
// K2: adjacency -> phase-interleaved bitmask + softmax denominators l[i].
// mask layout: word (i, jb, ph) bit b  <->  adj[i][jb*256 + b*4 + ph] > 0.
// ---------------------------------------------------------------------------
__global__ __launch_bounds__(256) void k2_mask_l(
    const float* __restrict__ adj, const float* __restrict__ s_src,
    const float* __restrict__ s_dst, uint64_t* __restrict__ mask,
    float* __restrict__ l_out)
{
    const int i = blockIdx.x;
    const int t = threadIdx.x, w = t >> 6, ln = t & 63;
    const float si = s_src[i];
    const float4* rowv = (const float4*)(adj + (size_t)i * N_NODES);
    const float4* sdv  = (const float4*)s_dst;
    float acc = 0.f;
    #pragma unroll
    for (int it = 0; it < 8; it++) {
        int jb = it * 4 + w;          // 256-j block, 0..31
        int v4 = jb * 64 + ln;
        float4 a  = rowv[v4];
        float4 sd = sdv[v4];
        uint64_t b0 = __ballot(a.x > 0.f);
        uint64_t b1 = __ballot(a.y > 0.f);
        uint64_t b2 = __ballot(a.z > 0.f);
        uint64_t b3 = __ballot(a.w > 0.f);
        if (ln == 0) {
            uint64_t* mw = mask + (size_t)i * 128 + jb * 4;
            mw[0] = b0; mw[1] = b1; mw[2] = b2; mw[3] = b3;
        }
        float x, e;
        x = si + sd.x; e = fmaxf(x, ALPHA * x); if (a.x > 0.f) acc += __expf(e);
        x = si + sd.y; e = fmaxf(x, ALPHA * x); if (a.y > 0.f) acc += __expf(e);
        x = si + sd.z; e = fmaxf(x, ALPHA * x); if (a.z > 0.f) acc += __expf(e);
        x = si + sd.w; e = fmaxf(x, ALPHA * x); if (a.w > 0.f) acc += __expf(e);
    }
    #pragma unroll
    for (int off = 32; off >= 1; off >>= 1) acc += __shfl_xor(acc, off, 64);
    __shared__ float red[4];
    if (ln == 0) red[w] = acc;
    __syncthreads();
    if (t == 0) l_out[i] = (red[0] + red[1]) + (red[2] + red[3]);
}

// ---------------------------------------------------------------------------
// K3: (attention @ Wh) bf16 MFMA GEMM + att-store EPILOGUE.
// grid (256 rb, 4 jc), 256 thr. Block: 32 rows x 2048 j, 64 iters of BK=32.
// KEY (round-4 lesson): vmcnt retires IN ORDER, so any global store issued
// inside the loop poisons the DMA wait (HBM-write ack latency lands on the
// critical path -> ~6k cy/barrier across rounds 0-4). Therefore the main
// loop does NO global stores: its VMEM queue holds ONLY the 4 staging DMAs
// -> vmcnt(0)+barrier is clean (~300 cy, covered by compute).
// The att tile (32x2048) is recomputed from LDS tables (sdt/mtab/ssrc/sinvl)
// in a store-only epilogue: pure NT-store burst, never waited on (kernel end
// drains it), overlapping other resident blocks' MFMA loops.
// Waves (mh, nh): mh = row half, nh = n half. acc[8], direct partial store.
// LDS ~= 48.8 KB -> 3 blocks/CU (12 waves).
// ---------------------------------------------------------------------------
__global__ __launch_bounds__(256, 3) void k3_att_gemm(
    const uint64_t* __restrict__ mask, const float* __restrict__ s_src,
    const float* __restrict__ s_dst, const float* __restrict__ l_in,
    const uint16_t* __restrict__ whf, float* __restrict__ att_out,
    float* __restrict__ partial)
{
    const int rb = blockIdx.x, jc = blockIdx.y;
    const int i0 = rb * 32, jbase = jc * 2048;
    const int t = threadIdx.x, w = t >> 6, ln = t & 63;
    const int mh = w & 1, nh = w >> 1;

    __shared__ uint16_t whf_lds[2][8192];   // 2 x 16 KB
    __shared__ float    sdt[2048];          // 8 KB: s_dst[jbase .. +2048)
    __shared__ uint64_t mtab[32 * 33];      // 8.25 KB: 32 rows x 32 words, pad 33
    __shared__ float    ssrc[32], sinvl[32];

    // ---- prologue: stage tables + tile 0 ----
    {
        // s_dst table: 2048 floats, 8 floats/thread
        const float4* s4 = (const float4*)(s_dst + jbase);
        ((float4*)sdt)[t * 2]     = s4[t * 2];
        ((float4*)sdt)[t * 2 + 1] = s4[t * 2 + 1];
        // mask table: row r = t>>3 gets words [(t&7)*4 .. +4)
        int r = t >> 3, c = (t & 7) * 4;
        const uint64_t* mr = mask + (size_t)(i0 + r) * 128 + (jbase >> 8) * 4 + c;
        uint64_t m0 = mr[0], m1 = mr[1], m2 = mr[2], m3 = mr[3];
        uint64_t* md = &mtab[r * 33 + c];
        md[0] = m0; md[1] = m1; md[2] = m2; md[3] = m3;
        // per-row scalars for the epilogue
        if (t < 32) { ssrc[t] = s_src[i0 + t]; sinvl[t] = 1.0f / l_in[i0 + t]; }
        // whf tile 0 (16 KB, 4 KB per wave)
        const uint16_t* src = whf + ((size_t)(jbase >> 5)) * 8192;
        #pragma unroll
        for (int q = 0; q < 4; q++) {
            int cchunk = w * 4 + q;
            async_copy16(src + (size_t)cchunk * 512 + ln * 8,
                         &whf_lds[0][cchunk * 512]);
        }
        __builtin_amdgcn_sched_barrier(0);
    }

    const int m   = mh * 16 + (ln & 15);    // row within block, 0..31
    const int kof = (ln >> 4) * 8;          // 0,8,16,24
    const int gi  = i0 + m;

    const float sim = s_src[gi];
    const float il  = 1.0f / l_in[gi];

    f32x4 acc[8];
    #pragma unroll
    for (int b = 0; b < 8; b++) acc[b] = (f32x4){0.f, 0.f, 0.f, 0.f};

    __syncthreads();   // tables + tile 0 ready (full drain, once)

    uint64_t mwv[4];

    for (int it = 0; it < 64; it++) {
        const int cur = it & 1;

        // stage NEXT tile (the ONLY VMEM ops in the loop)
        if (it < 63) {
            const uint16_t* src =
                whf + ((size_t)(jbase >> 5) + it + 1) * 8192;
            #pragma unroll
            for (int q = 0; q < 4; q++) {
                int cchunk = w * 4 + q;
                async_copy16(src + (size_t)cchunk * 512 + ln * 8,
                             &whf_lds[cur ^ 1][cchunk * 512]);
            }
        }
        __builtin_amdgcn_sched_barrier(0);

        // mask words for this 256-j group (LDS, bank-spread by pad 33)
        if ((it & 7) == 0) {
            const uint64_t* mp = &mtab[m * 33 + (it >> 3) * 4];
            mwv[0] = mp[0]; mwv[1] = mp[1]; mwv[2] = mp[2]; mwv[3] = mp[3];
        }

        // s_dst from LDS table
        const float* sp = sdt + it * 32 + kof;
        float4 sd0 = *(const float4*)sp;
        float4 sd1 = *(const float4*)(sp + 4);
        float sdv[8] = {sd0.x, sd0.y, sd0.z, sd0.w, sd1.x, sd1.y, sd1.z, sd1.w};

        const int bbase = ((it & 7) << 3) + (kof >> 2);
        float p[8];
        #pragma unroll
        for (int jj = 0; jj < 8; jj++) {
            float x  = sim + sdv[jj];
            float e  = fmaxf(x, ALPHA * x);
            float pe = __expf(e) * il;
            int bidx = bbase + (jj >> 2);
            p[jj] = ((mwv[jj & 3] >> bidx) & 1ull) ? pe : 0.f;
        }

        // pack A-fragment to bf16
        union { bf16x8 v; uint32_t u[4]; } pk;
        #pragma unroll
        for (int q = 0; q < 4; q++)
            pk.u[q] = f32_to_bf16(p[2 * q]) | (f32_to_bf16(p[2 * q + 1]) << 16);
        bf16x8 af = pk.v;

        // B-fragments from LDS (this wave's nh half: 8 x 1 KB)
        const uint16_t* bl = &whf_lds[cur][nh * 8 * 512 + ln * 8];
        #pragma unroll
        for (int nl = 0; nl < 8; nl++) {
            bf16x8 bfr = *(const bf16x8*)(bl + nl * 512);
            acc[nl] = __builtin_amdgcn_mfma_f32_16x16x32_bf16(af, bfr, acc[nl], 0, 0, 0);
        }

        // clean wait: only this iter's 4 DMAs are outstanding
        asm volatile("s_waitcnt vmcnt(0)" ::: "memory");
        __builtin_amdgcn_s_barrier();
    }

    // ---- GEMM epilogue: partial[jc] store ----
    // C/D frag: col = lane&15, row = (lane>>4)*4 + reg.
    {
        float* pbase = partial + (size_t)jc * ((size_t)N_NODES * OUT_F);
        const int gr0 = i0 + mh * 16 + (ln >> 4) * 4;
        #pragma unroll
        for (int nl = 0; nl < 8; nl++) {
            int gc = nh * 128 + nl * 16 + (ln & 15);
            #pragma unroll
            for (int r = 0; r < 4; r++)
                pbase[(size_t)(gr0 + r) * OUT_F + gc] = acc[nl][r];
        }
    }

    // ---- att epilogue: recompute P*il for the 32x2048 tile, NT-stream it.
    // iter k: row = k>>1, col = (k&1)*1024 + t*4 (4 KB coalesced per iter).
    // mask word reads are wave-broadcast (same 4 words per wave); bit = t&63.
    #pragma unroll 4
    for (int k = 0; k < 64; k++) {
        int row = k >> 1;
        int col = ((k & 1) << 10) + t * 4;
        float si  = ssrc[row];
        float ilr = sinvl[row];
        const uint64_t* mwp = &mtab[row * 33 + ((col >> 8) << 2)];
        int b = t & 63;
        float4 sd4 = *(const float4*)&sdt[col];
        float sdv4[4] = {sd4.x, sd4.y, sd4.z, sd4.w};
        float o[4];
        #pragma unroll
        for (int d = 0; d < 4; d++) {
            float x  = si + sdv4[d];
            float e  = fmaxf(x, ALPHA * x);
            float pe = __expf(e) * ilr;
            o[d] = ((mwp[d] >> b) & 1ull) ? pe : 0.f;
        }
        float* go = att_out + (size_t)(i0 + row) * N_NODES + jbase + col;
        __builtin_nontemporal_store(*(f32x4*)o, (f32x4*)go);
    }
    // no wait after the store burst: kernel end drains it off-critical-path
}

// ---------------------------------------------------------------------------
// K4: h_prime = sum of 4 split-K partials
// ---------------------------------------------------------------------------
__global__ __launch_bounds__(256) void k4_reduce(
    const float* __restrict__ partial, float* __restrict__ hp)
{
    const size_t S = (size_t)N_NODES * OUT_F;
    int idx = (blockIdx.x * 256 + threadIdx.x) * 4;
    float4 a = *(const float4*)(partial + idx);
    float4 b = *(const float4*)(partial + S + idx);
    float4 c = *(const float4*)(partial + 2 * S + idx);
    float4 d = *(const float4*)(partial + 3 * S + idx);
    float4 o;
    o.x = (a.x + b.x) + (c.x + d.x);
    o.y = (a.y + b.y) + (c.y + d.y);
    o.z = (a.z + b.z) + (c.z + d.z);
    o.w = (a.w + b.w) + (c.w + d.w);
    *(float4*)(hp + idx) = o;
}

extern "C" void kernel_launch(void* const* d_in, const int* in_sizes, int n_in,
                              void* d_out, int out_size, void* d_ws, size_t ws_size,
                              hipStream_t stream) {
    (void)in_sizes; (void)n_in; (void)out_size; (void)ws_size;
    const float* h     = (const float*)d_in[0];
    const float* adj   = (const float*)d_in[1];
    const float* W     = (const float*)d_in[2];
    const float* a_vec = (const float*)d_in[3];

    char* ws = (char*)d_ws;
    uint16_t* whf  = (uint16_t*)(ws);                          // 4 MB
    uint64_t* mask = (uint64_t*)(ws + ((size_t)4 << 20));      // 8 MB
    float* partial = (float*)(ws + ((size_t)12 << 20));        // 32 MB
    float* w12     = (float*)(ws + ((size_t)44 << 20));        // 4 KB
    float* s_src   = (float*)(ws + ((size_t)44 << 20) + 16384);
    float* s_dst   = (float*)(ws + ((size_t)44 << 20) + 16384 + 32768);
    float* l_buf   = (float*)(ws + ((size_t)44 << 20) + 16384 + 65536);

    float* hp  = (float*)d_out;
    float* att = hp + (size_t)N_NODES * OUT_F;

    hipMemsetAsync(w12, 0, 4096, stream);
    k0_wvec<<<32, 256, 0, stream>>>(W, a_vec, w12);
    ks_svec<<<2048, 256, 0, stream>>>(h, w12, s_src, s_dst);
    k1_wh_pack<<<dim3(4, 128), 256, 0, stream>>>(h, W, whf);
    k2_mask_l<<<8192, 256, 0, stream>>>(adj, s_src, s_dst, mask, l_buf);
    k3_att_gemm<<<dim3(256, 4), 256, 0, stream>>>(mask, s_src, s_dst, l_buf, whf, att, partial);
    k4_reduce<<<2048, 256, 0, stream>>>(partial, hp);
}

// Round 6
// 612.300 us; speedup vs baseline: 1.1873x; 1.0238x over previous
//
#include <hip/hip_runtime.h>
#include <stdint.h>

#define N_NODES 8192
#define IN_F    512
#define OUT_F   256
#define ALPHA   0.2f

typedef __attribute__((ext_vector_type(8))) short bf16x8;
typedef __attribute__((ext_vector_type(4))) float f32x4;

__device__ __forceinline__ uint32_t f32_to_bf16(float f) {
    union { float f; uint32_t u; } v; v.f = f;
    uint32_t u = v.u;
    return (u + 0x7fffu + ((u >> 16) & 1u)) >> 16;   // RNE
}

// async global->LDS, 16B per lane; LDS dest = uniform base + lane*16
__device__ __forceinline__ void async_copy16(const void* g, void* l) {
    __builtin_amdgcn_global_load_lds(
        (const __attribute__((address_space(1))) uint32_t*)g,
        (__attribute__((address_space(3))) uint32_t*)l, 16, 0, 0);
}

// ---------------------------------------------------------------------------
// K0: w1 = W^T a1, w2 = W^T a2  (w12[0:512]=w1, w12[512:1024]=w2)
// ---------------------------------------------------------------------------
__global__ __launch_bounds__(256) void k0_wvec(
    const float* __restrict__ W, const float* __restrict__ a_vec,
    float* __restrict__ w12)
{
    const int t  = threadIdx.x;
    const int nb = blockIdx.x * 8;
    float a1lo = 0.f, a1hi = 0.f, a2lo = 0.f, a2hi = 0.f;
    #pragma unroll
    for (int q = 0; q < 8; q++) {
        int n = nb + q;
        float lo = W[(size_t)n * IN_F + t];
        float hi = W[(size_t)n * IN_F + t + 256];
        float a1 = a_vec[n], a2 = a_vec[OUT_F + n];
        a1lo = fmaf(lo, a1, a1lo); a1hi = fmaf(hi, a1, a1hi);
        a2lo = fmaf(lo, a2, a2lo); a2hi = fmaf(hi, a2, a2hi);
    }
    atomicAdd(&w12[t], a1lo);       atomicAdd(&w12[t + 256], a1hi);
    atomicAdd(&w12[512 + t], a2lo); atomicAdd(&w12[512 + t + 256], a2hi);
}

// ---------------------------------------------------------------------------
// Ks: s_src[i] = h[i] . w1 ; s_dst[i] = h[i] . w2   (1 wave per row)
// ---------------------------------------------------------------------------
__global__ __launch_bounds__(256) void ks_svec(
    const float* __restrict__ h, const float* __restrict__ w12,
    float* __restrict__ s_src, float* __restrict__ s_dst)
{
    __shared__ float sw[1024];
    const int t = threadIdx.x;
    #pragma unroll
    for (int q = 0; q < 4; q++) sw[q * 256 + t] = w12[q * 256 + t];
    __syncthreads();
    const int w = t >> 6, ln = t & 63;
    const int i = blockIdx.x * 4 + w;
    const float* hr = h + (size_t)i * IN_F + ln * 8;
    float4 h0 = *(const float4*)hr;
    float4 h1 = *(const float4*)(hr + 4);
    const float* w1 = sw + ln * 8;
    const float* w2 = sw + 512 + ln * 8;
    float v1 = h0.x*w1[0] + h0.y*w1[1] + h0.z*w1[2] + h0.w*w1[3]
             + h1.x*w1[4] + h1.y*w1[5] + h1.z*w1[6] + h1.w*w1[7];
    float v2 = h0.x*w2[0] + h0.y*w2[1] + h0.z*w2[2] + h0.w*w2[3]
             + h1.x*w2[4] + h1.y*w2[5] + h1.z*w2[6] + h1.w*w2[7];
    #pragma unroll
    for (int off = 32; off >= 1; off >>= 1) {
        v1 += __shfl_xor(v1, off, 64);
        v2 += __shfl_xor(v2, off, 64);
    }
    if (ln == 0) { s_src[i] = v1; s_dst[i] = v2; }
}

// ---------------------------------------------------------------------------
// K1: Wh = h @ W^T (fp32) -> whf bf16 in MFMA-B-fragment-major layout.
// chunk c = (j>>5)*16 + (n>>4); within: lane = (n&15) + ((j>>3)&3)*16,
// element = lane*8 + (j&7).   grid (4 colblk, 128 rowblk), 256 thr, 4x4/thr.
// ---------------------------------------------------------------------------
__global__ __launch_bounds__(256) void k1_wh_pack(
    const float* __restrict__ h, const float* __restrict__ W,
    uint16_t* __restrict__ whf)
{
    const int n0 = blockIdx.x * 64, i0 = blockIdx.y * 64;
    const int t  = threadIdx.x;
    const int tn = t & 15, tm = t >> 4;

    __shared__ float As[32][68];
    __shared__ float Bs[32][68];

    float acc[4][4];
    #pragma unroll
    for (int i = 0; i < 4; i++)
        #pragma unroll
        for (int j = 0; j < 4; j++) acc[i][j] = 0.f;

    for (int k0 = 0; k0 < IN_F; k0 += 32) {
        __syncthreads();
        #pragma unroll
        for (int q = 0; q < 2; q++) {
            int u   = q * 256 + t;
            int row = u >> 3;
            int kf  = (u & 7) * 4;
            float4 va = *(const float4*)&h[(size_t)(i0 + row) * IN_F + k0 + kf];
            As[kf + 0][row] = va.x; As[kf + 1][row] = va.y;
            As[kf + 2][row] = va.z; As[kf + 3][row] = va.w;
            float4 vb = *(const float4*)&W[(size_t)(n0 + row) * IN_F + k0 + kf];
            Bs[kf + 0][row] = vb.x; Bs[kf + 1][row] = vb.y;
            Bs[kf + 2][row] = vb.z; Bs[kf + 3][row] = vb.w;
        }
        __syncthreads();
        #pragma unroll
        for (int kk = 0; kk < 32; kk++) {
            float a[4], b[4];
            *(float4*)a = *(const float4*)&As[kk][tm * 4];
            *(float4*)b = *(const float4*)&Bs[kk][tn * 4];
            #pragma unroll
            for (int i = 0; i < 4; i++)
                #pragma unroll
                for (int j = 0; j < 4; j++) acc[i][j] = fmaf(a[i], b[j], acc[i][j]);
        }
    }

    #pragma unroll
    for (int ii = 0; ii < 4; ii++) {
        int gr = i0 + tm * 4 + ii;
        int ck = gr >> 5;
        int lr = (gr >> 3) & 3;
        int jj = gr & 7;
        #pragma unroll
        for (int jn = 0; jn < 4; jn++) {
            int gc   = n0 + tn * 4 + jn;
            int c    = ck * 16 + (gc >> 4);
            int lane = (gc & 15) + lr * 16;
            whf[(size_t)c * 512 + lane * 8 + jj] = (uint16_t)f32_to_bf16(acc[ii][jn]);
        }
    }
}

// ---------------------------------------------------------------------------
// K2: FUSED adjacency pass: bitmask + softmax denominator + ATT WRITE.
// Pass 1: read adj row, ballot -> mask words (LDS + global), masked exp-sum.
// Pass 2: recompute exp(e)*il from LDS mask words + L2-resident s_dst and
// stream the full att row out with REGULAR stores (write-combines through
// L2; the adj lines being evicted are read-once/dead). Read 256MB + write
// 256MB overlapped on the HBM bus in ONE kernel -- the att write no longer
// defines a separate kernel's duration (round-5 lesson: att stores capped
// k3 at ~1.9 TB/s; GEMM was idling behind them).
// ---------------------------------------------------------------------------
__global__ __launch_bounds__(256) void k2_mask_att(
    const float* __restrict__ adj, const float* __restrict__ s_src,
    const float* __restrict__ s_dst, uint64_t* __restrict__ mask,
    float* __restrict__ l_out, float* __restrict__ att_out)
{
    const int i = blockIdx.x;
    const int t = threadIdx.x, w = t >> 6, ln = t & 63;
    const float si = s_src[i];
    const float4* rowv = (const float4*)(adj + (size_t)i * N_NODES);
    const float4* sdv  = (const float4*)s_dst;

    __shared__ uint64_t mtab[128];
    __shared__ float red[4];

    float acc = 0.f;
    #pragma unroll
    for (int it = 0; it < 8; it++) {
        int jb = it * 4 + w;          // 256-j block, 0..31
        int v4 = jb * 64 + ln;
        float4 a  = rowv[v4];
        float4 sd = sdv[v4];
        uint64_t b0 = __ballot(a.x > 0.f);
        uint64_t b1 = __ballot(a.y > 0.f);
        uint64_t b2 = __ballot(a.z > 0.f);
        uint64_t b3 = __ballot(a.w > 0.f);
        if (ln == 0) {
            uint64_t* mw = mask + (size_t)i * 128 + jb * 4;
            mw[0] = b0; mw[1] = b1; mw[2] = b2; mw[3] = b3;
            uint64_t* ml = &mtab[jb * 4];
            ml[0] = b0; ml[1] = b1; ml[2] = b2; ml[3] = b3;
        }
        float x, e;
        x = si + sd.x; e = fmaxf(x, ALPHA * x); if (a.x > 0.f) acc += __expf(e);
        x = si + sd.y; e = fmaxf(x, ALPHA * x); if (a.y > 0.f) acc += __expf(e);
        x = si + sd.z; e = fmaxf(x, ALPHA * x); if (a.z > 0.f) acc += __expf(e);
        x = si + sd.w; e = fmaxf(x, ALPHA * x); if (a.w > 0.f) acc += __expf(e);
    }
    #pragma unroll
    for (int off = 32; off >= 1; off >>= 1) acc += __shfl_xor(acc, off, 64);
    if (ln == 0) red[w] = acc;
    __syncthreads();   // red + mtab visible

    float l = (red[0] + red[1]) + (red[2] + red[3]);
    if (t == 0) l_out[i] = l;
    const float il = 1.0f / l;

    // pass 2: att row. group g: j0 = g*1024 + t*4; jb = j0>>8 is wave-
    // uniform -> mtab reads broadcast; bit index = ln; word = jb*4 + d.
    float* arow = att_out + (size_t)i * N_NODES;
    #pragma unroll
    for (int g = 0; g < 8; g++) {
        int j0 = g * 1024 + t * 4;
        int jb = j0 >> 8;
        const uint64_t* mwp = &mtab[jb * 4];
        uint64_t m0 = mwp[0], m1 = mwp[1], m2 = mwp[2], m3 = mwp[3];
        float4 sd4 = sdv[j0 >> 2];
        float o[4];
        float x, e;
        x = si + sd4.x; e = fmaxf(x, ALPHA * x);
        o[0] = ((m0 >> ln) & 1ull) ? __expf(e) * il : 0.f;
        x = si + sd4.y; e = fmaxf(x, ALPHA * x);
        o[1] = ((m1 >> ln) & 1ull) ? __expf(e) * il : 0.f;
        x = si + sd4.z; e = fmaxf(x, ALPHA * x);
        o[2] = ((m2 >> ln) & 1ull) ? __expf(e) * il : 0.f;
        x = si + sd4.w; e = fmaxf(x, ALPHA * x);
        o[3] = ((m3 >> ln) & 1ull) ? __expf(e) * il : 0.f;
        *(float4*)(arow + j0) = *(float4*)o;   // regular (cached) store
    }
}

// ---------------------------------------------------------------------------
// K3: PURE masked-attention GEMM (att written by K2 now).
// grid (256 rb, 4 jc), 256 thr. Block: 32 rows x 2048 j, 64 iters of BK=32.
// Main-loop VMEM queue: 4 staging DMAs (+ 4 L2-hit mask loads every 8th
// iter) -- no stores, so vmcnt(0)+barrier is clean (~300cy, covered).
// il deferred to the epilogue (per-output-row scale) -> no per-iter mul.
// LDS = 32K whf dbuf + 8K sdt = EXACTLY 40960 B -> 4 blocks/CU; grid 1024 =
// exactly 4 blocks/CU co-resident, no tail.
// Waves (mh, nh): mh = row half, nh = n half; acc[8]; direct partial store.
// ---------------------------------------------------------------------------
__global__ __launch_bounds__(256, 4) void k3_att_gemm(
    const uint64_t* __restrict__ mask, const float* __restrict__ s_src,
    const float* __restrict__ s_dst, const float* __restrict__ l_in,
    const uint16_t* __restrict__ whf, float* __restrict__ partial)
{
    const int rb = blockIdx.x, jc = blockIdx.y;
    const int i0 = rb * 32, jbase = jc * 2048;
    const int t = threadIdx.x, w = t >> 6, ln = t & 63;
    const int mh = w & 1, nh = w >> 1;

    __shared__ uint16_t whf_lds[2][8192];   // 32 KB
    __shared__ float    sdt[2048];          // 8 KB  -> total exactly 40 KB

    // ---- prologue: stage sdt + tile 0 ----
    {
        const float4* s4 = (const float4*)(s_dst + jbase);
        ((float4*)sdt)[t * 2]     = s4[t * 2];
        ((float4*)sdt)[t * 2 + 1] = s4[t * 2 + 1];
        const uint16_t* src = whf + ((size_t)(jbase >> 5)) * 8192;
        #pragma unroll
        for (int q = 0; q < 4; q++) {
            int cchunk = w * 4 + q;
            async_copy16(src + (size_t)cchunk * 512 + ln * 8,
                         &whf_lds[0][cchunk * 512]);
        }
        __builtin_amdgcn_sched_barrier(0);
    }

    const int m   = mh * 16 + (ln & 15);    // row within block, 0..31
    const int kof = (ln >> 4) * 8;          // 0,8,16,24
    const int gi  = i0 + m;

    const float sim = s_src[gi];

    f32x4 acc[8];
    #pragma unroll
    for (int b = 0; b < 8; b++) acc[b] = (f32x4){0.f, 0.f, 0.f, 0.f};

    __syncthreads();   // sdt + tile 0 ready (full drain, once)

    uint64_t mwv[4];

    for (int it = 0; it < 64; it++) {
        const int cur = it & 1;

        // stage NEXT tile (the only recurring VMEM ops)
        if (it < 63) {
            const uint16_t* src =
                whf + ((size_t)(jbase >> 5) + it + 1) * 8192;
            #pragma unroll
            for (int q = 0; q < 4; q++) {
                int cchunk = w * 4 + q;
                async_copy16(src + (size_t)cchunk * 512 + ln * 8,
                             &whf_lds[cur ^ 1][cchunk * 512]);
            }
        }
        __builtin_amdgcn_sched_barrier(0);

        // mask words for this 256-j group (32B contiguous, L2 hit)
        if ((it & 7) == 0) {
            const uint64_t* mp =
                mask + (size_t)gi * 128 + (jbase >> 8) * 4 + (it >> 3) * 4;
            mwv[0] = mp[0]; mwv[1] = mp[1]; mwv[2] = mp[2]; mwv[3] = mp[3];
        }

        // s_dst from LDS table
        const float* sp = sdt + it * 32 + kof;
        float4 sd0 = *(const float4*)sp;
        float4 sd1 = *(const float4*)(sp + 4);
        float sdv[8] = {sd0.x, sd0.y, sd0.z, sd0.w, sd1.x, sd1.y, sd1.z, sd1.w};

        const int bbase = ((it & 7) << 3) + (kof >> 2);
        float p[8];
        #pragma unroll
        for (int jj = 0; jj < 8; jj++) {
            float x  = sim + sdv[jj];
            float e  = fmaxf(x, ALPHA * x);
            float pe = __expf(e);            // il deferred to epilogue
            int bidx = bbase + (jj >> 2);
            p[jj] = ((mwv[jj & 3] >> bidx) & 1ull) ? pe : 0.f;
        }

        // pack A-fragment to bf16
        union { bf16x8 v; uint32_t u[4]; } pk;
        #pragma unroll
        for (int q = 0; q < 4; q++)
            pk.u[q] = f32_to_bf16(p[2 * q]) | (f32_to_bf16(p[2 * q + 1]) << 16);
        bf16x8 af = pk.v;

        // B-fragments from LDS (this wave's nh half: 8 x 1 KB)
        const uint16_t* bl = &whf_lds[cur][nh * 8 * 512 + ln * 8];
        #pragma unroll
        for (int nl = 0; nl < 8; nl++) {
            bf16x8 bfr = *(const bf16x8*)(bl + nl * 512);
            acc[nl] = __builtin_amdgcn_mfma_f32_16x16x32_bf16(af, bfr, acc[nl], 0, 0, 0);
        }

        // clean wait: only this iter's DMAs (+ occasional L2 loads)
        asm volatile("s_waitcnt vmcnt(0)" ::: "memory");
        __builtin_amdgcn_s_barrier();
    }

    // epilogue: per-output-row 1/l scale + store.
    // C/D frag: col = lane&15, row = (lane>>4)*4 + reg.
    float* pbase = partial + (size_t)jc * ((size_t)N_NODES * OUT_F);
    const int gr0 = i0 + mh * 16 + (ln >> 4) * 4;
    float il4[4];
    #pragma unroll
    for (int r = 0; r < 4; r++) il4[r] = 1.0f / l_in[gr0 + r];
    #pragma unroll
    for (int nl = 0; nl < 8; nl++) {
        int gc = nh * 128 + nl * 16 + (ln & 15);
        #pragma unroll
        for (int r = 0; r < 4; r++)
            pbase[(size_t)(gr0 + r) * OUT_F + gc] = acc[nl][r] * il4[r];
    }
}

// ---------------------------------------------------------------------------
// K4: h_prime = sum of 4 split-K partials
// ---------------------------------------------------------------------------
__global__ __launch_bounds__(256) void k4_reduce(
    const float* __restrict__ partial, float* __restrict__ hp)
{
    const size_t S = (size_t)N_NODES * OUT_F;
    int idx = (blockIdx.x * 256 + threadIdx.x) * 4;
    float4 a = *(const float4*)(partial + idx);
    float4 b = *(const float4*)(partial + S + idx);
    float4 c = *(const float4*)(partial + 2 * S + idx);
    float4 d = *(const float4*)(partial + 3 * S + idx);
    float4 o;
    o.x = (a.x + b.x) + (c.x + d.x);
    o.y = (a.y + b.y) + (c.y + d.y);
    o.z = (a.z + b.z) + (c.z + d.z);
    o.w = (a.w + b.w) + (c.w + d.w);
    *(float4*)(hp + idx) = o;
}

extern "C" void kernel_launch(void* const* d_in, const int* in_sizes, int n_in,
                              void* d_out, int out_size, void* d_ws, size_t ws_size,
                              hipStream_t stream) {
    (void)in_sizes; (void)n_in; (void)out_size; (void)ws_size;
    const float* h     = (const float*)d_in[0];
    const float* adj   = (const float*)d_in[1];
    const float* W     = (const float*)d_in[2];
    const float* a_vec = (const float*)d_in[3];

    char* ws = (char*)d_ws;
    uint16_t* whf  = (uint16_t*)(ws);                          // 4 MB
    uint64_t* mask = (uint64_t*)(ws + ((size_t)4 << 20));      // 8 MB
    float* partial = (float*)(ws + ((size_t)12 << 20));        // 32 MB
    float* w12     = (float*)(ws + ((size_t)44 << 20));        // 4 KB
    float* s_src   = (float*)(ws + ((size_t)44 << 20) + 16384);
    float* s_dst   = (float*)(ws + ((size_t)44 << 20) + 16384 + 32768);
    float* l_buf   = (float*)(ws + ((size_t)44 << 20) + 16384 + 65536);

    float* hp  = (float*)d_out;
    float* att = hp + (size_t)N_NODES * OUT_F;

    hipMemsetAsync(w12, 0, 4096, stream);
    k0_wvec<<<32, 256, 0, stream>>>(W, a_vec, w12);
    ks_svec<<<2048, 256, 0, stream>>>(h, w12, s_src, s_dst);
    k1_wh_pack<<<dim3(4, 128), 256, 0, stream>>>(h, W, whf);
    k2_mask_att<<<8192, 256, 0, stream>>>(adj, s_src, s_dst, mask, l_buf, att);
    k3_att_gemm<<<dim3(256, 4), 256, 0, stream>>>(mask, s_src, s_dst, l_buf, whf, partial);
    k4_reduce<<<2048, 256, 0, stream>>>(partial, hp);
}